// Round 1
// 197.672 us; speedup vs baseline: 1.0803x; 1.0803x over previous
//
#include <hip/hip_runtime.h>

#define B_    2
#define N_    2304
#define C_    768
#define HEADS 12
#define D_    64
#define F3    2304
#define M_    (B_*N_)        // 4608
#define SPLITS 2
#define KSPAN (N_/SPLITS)    // 1152
// SCALE(0.125) * log2(e) folded into Q at qkv epilogue:
#define QSCALE 0.18033688011112042f

typedef __attribute__((ext_vector_type(8)))  short bfrag;    // 8 x bf16 (4 VGPR)
typedef __attribute__((ext_vector_type(4)))  float ffrag;    // 16x16 acc
typedef __attribute__((ext_vector_type(16))) float ffrag16;  // 32x32 acc
typedef __attribute__((ext_vector_type(4)))  unsigned ufrag; // 4 x b32 = 8 bf16
typedef __attribute__((ext_vector_type(2)))  unsigned uint2v;

__device__ __forceinline__ short f2bf(float f) {
    unsigned u = __float_as_uint(f);
    u += 0x7fff + ((u >> 16) & 1);          // RNE
    return (short)(u >> 16);
}

__device__ __forceinline__ void gl2lds16(const void* g, void* l) {
    __builtin_amdgcn_global_load_lds(
        (const __attribute__((address_space(1))) void*)g,
        (__attribute__((address_space(3))) void*)l, 16, 0, 0);
}

// trunc-pack two fp32 -> (bf16(a) low | bf16(b) high) in ONE v_perm_b32.
// bias-safe here because numerator (PV) and denominator (ones-MFMA) both
// consume the same truncated fragments -> common bias cancels in the ratio.
__device__ __forceinline__ unsigned pktrunc(float a, float b) {
    return __builtin_amdgcn_perm(__float_as_uint(a), __float_as_uint(b),
                                 0x03020706u);
}

// ---------------------------------------------------------------------------
// Fused fp32 -> bf16 cast of x, qkv_w, proj_w (dsts contiguous in ws).
// ---------------------------------------------------------------------------
__global__ __launch_bounds__(256) void cast_all(const float* __restrict__ x,
                                                const float* __restrict__ qw,
                                                const float* __restrict__ pw,
                                                short* __restrict__ dst) {
    const int nx4 = (M_*C_)/4, nq4 = (F3*C_)/4, np4 = (C_*C_)/4;
    int i = blockIdx.x * 256 + threadIdx.x;
    if (i >= nx4 + nq4 + np4) return;
    const float* src; int off;
    if (i < nx4)            { src = x;  off = i; }
    else if (i < nx4 + nq4) { src = qw; off = i - nx4; }
    else                    { src = pw; off = i - nx4 - nq4; }
    float4 v = ((const float4*)src)[off];
    short4 o;
    o.x = f2bf(v.x); o.y = f2bf(v.y); o.z = f2bf(v.z); o.w = f2bf(v.w);
    ((short4*)dst)[i] = o;
}

// ---------------------------------------------------------------------------
// QKV GEMM: qkv[m][f] = sum_c x[m][c]*w[f][c]  (NT), m97 structure.
// Q stored pre-scaled by SCALE*log2e; V stored transposed [bh,d,n].
// ---------------------------------------------------------------------------
__global__ __launch_bounds__(256) void qkv_gemm(const short* __restrict__ xb,
                                                const short* __restrict__ wb,
                                                short* __restrict__ Qb,
                                                short* __restrict__ Kb,
                                                short* __restrict__ Vtb) {
    __shared__ short As[128*32];
    __shared__ short Bs[128*32];
    const int t = threadIdx.x;
    const int w = t >> 6, lane = t & 63;
    const int quad = lane >> 4, l15 = lane & 15;
    const int wr = w >> 1, wc = w & 1;
    const int m0 = blockIdx.y * 128, f0 = blockIdx.x * 128;

    ffrag acc[4][4] = {};

    for (int k0 = 0; k0 < C_; k0 += 32) {
        __syncthreads();
        #pragma unroll
        for (int r = 0; r < 2; ++r) {
            int seg = r*4 + w;
            int row = seg*16 + (lane >> 2);
            int kk  = (lane & 3) * 8;
            gl2lds16(xb + (size_t)(m0+row)*C_ + k0 + kk, As + seg*512);
            gl2lds16(wb + (size_t)(f0+row)*C_ + k0 + kk, Bs + seg*512);
        }
        __syncthreads();
        bfrag af[4], bf[4];
        #pragma unroll
        for (int i = 0; i < 4; ++i)
            af[i] = *(const bfrag*)(As + (wr*64 + i*16 + l15)*32 + quad*8);
        #pragma unroll
        for (int j = 0; j < 4; ++j)
            bf[j] = *(const bfrag*)(Bs + (wc*64 + j*16 + l15)*32 + quad*8);
        #pragma unroll
        for (int i = 0; i < 4; ++i)
            #pragma unroll
            for (int j = 0; j < 4; ++j)
                acc[i][j] = __builtin_amdgcn_mfma_f32_16x16x32_bf16(af[i], bf[j], acc[i][j], 0, 0, 0);
    }

    const int b   = m0 / N_;
    const int seg = f0 + wc*64;
    const int which = seg / C_;                  // 0=Q 1=K 2=V
    const int head  = (seg - which*C_) >> 6;
    const int bh    = b*HEADS + head;
    const int nbase = (m0 - b*N_) + wr*64 + quad*4;

    if (which == 0) {
        #pragma unroll
        for (int i = 0; i < 4; ++i) {
            int n0 = nbase + i*16;
            #pragma unroll
            for (int j = 0; j < 4; ++j) {
                int d = j*16 + l15;
                #pragma unroll
                for (int r = 0; r < 4; ++r)
                    Qb[((size_t)bh*N_ + n0 + r)*D_ + d] = f2bf(acc[i][j][r] * QSCALE);
            }
        }
    } else if (which == 1) {
        #pragma unroll
        for (int i = 0; i < 4; ++i) {
            int n0 = nbase + i*16;
            #pragma unroll
            for (int j = 0; j < 4; ++j) {
                int d = j*16 + l15;
                #pragma unroll
                for (int r = 0; r < 4; ++r)
                    Kb[((size_t)bh*N_ + n0 + r)*D_ + d] = f2bf(acc[i][j][r]);
            }
        }
    } else {
        #pragma unroll
        for (int i = 0; i < 4; ++i) {
            int n0 = nbase + i*16;
            #pragma unroll
            for (int j = 0; j < 4; ++j) {
                int d = j*16 + l15;
                short4 vv;
                vv.x = f2bf(acc[i][j][0]);
                vv.y = f2bf(acc[i][j][1]);
                vv.z = f2bf(acc[i][j][2]);
                vv.w = f2bf(acc[i][j][3]);
                *(short4*)(Vtb + ((size_t)bh*D_ + d)*N_ + n0) = vv;
            }
        }
    }
}

// ---------------------------------------------------------------------------
// Flash attention, 32x32x16 bf16 MFMA, no-max softmax, split-K over grid.z.
// v2: 4-wave blocks over 128 q-rows (K/V staged once per block), K/V LDS
// double-buffered with a 2-phase pipeline (prefetch tile t+1 before the
// compute of tile t; single barrier per tile — the compiler's vmcnt(0)
// drain at s_barrier is the wait). Q tile (16 KiB) overlays buffer set 1
// during the prologue only. P-fragment transpose now uses
// v_permlane32_swap_b32 (VALU) instead of ds_bpermute-based __shfl_xor:
// swap(q01_g, q01_{g+1}) returns BOTH output words (lo[0],lo[2]) in one op.
// Grid (B*H, N/128, SPLITS). Block 256 thr (4 waves), wave w: q-rows
// w*32..w*32+31 of the 128-row tile.
// LDS rows 128B, XOR-swizzled: chunk c of row r lives at (c ^ (r&7))*16B.
// 32x32 C layout: col = lane&31, row = (reg&3) + 8*(reg>>2) + 4*(lane>>5).
// ---------------------------------------------------------------------------
__global__ __launch_bounds__(256, 4) void attn_mfma(const short* __restrict__ Qb,
                                                    const short* __restrict__ Kb,
                                                    const short* __restrict__ Vtb,
                                                    float* __restrict__ Opart,
                                                    float* __restrict__ lpart) {
    // 32 KiB total: set s at lds + s*8192 shorts (K 4096 | V 4096).
    __shared__ short lds[16384];
    const int t = threadIdx.x;
    const int w = t >> 6, lane = t & 63;
    const int l31 = lane & 31, hi = lane >> 5;
    const int bh = blockIdx.x, q0 = blockIdx.y * 128;
    const int split = blockIdx.z;
    const int kbase = split * KSPAN;
    const size_t base = (size_t)bh * N_ * D_;
    const int lrow = lane >> 3;            // row within 8-row segment
    const int lc   = (lane & 7) ^ lrow;    // swizzled source chunk

    short* Qs = lds + 8192;                // overlays set 1

    // prologue: stage Q tile (128 x 64) into set1 region, K/V tile 0 into set0
    #pragma unroll
    for (int r = 0; r < 4; ++r) {
        int s = r*4 + w;
        gl2lds16(Qb + base + (size_t)(q0 + s*8 + lrow)*D_ + lc*8, Qs + s*512);
    }
    #pragma unroll
    for (int r = 0; r < 2; ++r) {
        int s = r*4 + w;
        int row = s*8 + lrow;
        gl2lds16(Kb  + base + (size_t)(kbase+row)*D_ + lc*8,    lds + s*512);
        gl2lds16(Vtb + (size_t)(bh*D_ + row)*N_ + kbase + lc*8, lds + 4096 + s*512);
    }
    __syncthreads();                       // Q + tile0 staged

    // hoist Q B-frags (loop-invariant)
    bfrag qf[4];
    {
        int row = w*32 + l31, r7 = row & 7;
        #pragma unroll
        for (int kc = 0; kc < 4; ++kc)
            qf[kc] = *(const bfrag*)(Qs + row*64 + ((kc*2 + hi) ^ r7)*8);
    }
    __syncthreads();                       // Q-frag reads done before set1 reuse

    // ones B-frag for the l (row-sum) MFMA
    bfrag vones;
    #pragma unroll
    for (int j = 0; j < 8; ++j) vones[j] = (short)0x3f80;

    ffrag16 oacc[2], lfr;
    #pragma unroll
    for (int r = 0; r < 16; ++r) { oacc[0][r] = 0.f; oacc[1][r] = 0.f; lfr[r] = 0.f; }

    const int NT = KSPAN / 64;             // 18
    for (int ti = 0; ti < NT; ++ti) {
        const int cur = ti & 1;
        const short* Kc = lds + cur*8192;
        const short* Vc = Kc + 4096;

        // issue next tile's staging into the other buffer set (hidden under
        // this tile's compute; drained by the trailing barrier)
        if (ti + 1 < NT) {
            short* Kn = lds + (cur^1)*8192;
            const int k0n = kbase + (ti+1)*64;
            #pragma unroll
            for (int r = 0; r < 2; ++r) {
                int s = r*4 + w;
                int row = s*8 + lrow;
                gl2lds16(Kb  + base + (size_t)(k0n+row)*D_ + lc*8,    Kn + s*512);
                gl2lds16(Vtb + (size_t)(bh*D_ + row)*N_ + k0n + lc*8, Kn + 4096 + s*512);
            }
        }

        ufrag pfr[4];                      // A-frags for PV, kc = kt*2 + {lo,hi}
        #pragma unroll
        for (int kt = 0; kt < 2; ++kt) {
            // S^T tile: rows k (reg-dist), cols q (lane)
            ffrag16 s;
            #pragma unroll
            for (int r = 0; r < 16; ++r) s[r] = 0.f;
            int row = kt*32 + l31, r7 = row & 7;
            __builtin_amdgcn_s_setprio(1);
            #pragma unroll
            for (int kc = 0; kc < 4; ++kc) {
                bfrag kf = *(const bfrag*)(Kc + row*64 + ((kc*2 + hi) ^ r7)*8);
                s = __builtin_amdgcn_mfma_f32_32x32x16_bf16(kf, qf[kc], s, 0, 0, 0);
            }
            __builtin_amdgcn_s_setprio(0);
            // p = 2^s; trunc-pack to bf16 pairs (k even-adjacent)
            #pragma unroll
            for (int r = 0; r < 16; ++r)
                s[r] = __builtin_amdgcn_exp2f(s[r]);
            // group g (regs 4g..4g+3) holds k_local = 8g + 4hi + {0..3}
            unsigned q01_0 = pktrunc(s[0],  s[1]),  q23_0 = pktrunc(s[2],  s[3]);
            unsigned q01_1 = pktrunc(s[4],  s[5]),  q23_1 = pktrunc(s[6],  s[7]);
            unsigned q01_2 = pktrunc(s[8],  s[9]),  q23_2 = pktrunc(s[10], s[11]);
            unsigned q01_3 = pktrunc(s[12], s[13]), q23_3 = pktrunc(s[14], s[15]);
            // v_permlane32_swap: {a',b'} with a' = [a.lo32 | b.lo32],
            // b' = [a.hi32 | b.hi32] — exactly the lo/hi fragment exchange.
            uint2v e0 = __builtin_amdgcn_permlane32_swap(q01_0, q01_1, false, false);
            uint2v e1 = __builtin_amdgcn_permlane32_swap(q23_0, q23_1, false, false);
            uint2v e2 = __builtin_amdgcn_permlane32_swap(q01_2, q01_3, false, false);
            uint2v e3 = __builtin_amdgcn_permlane32_swap(q23_2, q23_3, false, false);
            ufrag lo, hif;
            lo[0]  = e0[0]; lo[1]  = e1[0]; lo[2]  = e0[1]; lo[3]  = e1[1];
            hif[0] = e2[0]; hif[1] = e3[0]; hif[2] = e2[1]; hif[3] = e3[1];
            pfr[kt*2]     = lo;            // k_local 0-15  (P[q][8hi+j] form)
            pfr[kt*2 + 1] = hif;           // k_local 16-31
        }

        // O += P V ; l += P 1  (consumes the same truncated P frags)
        __builtin_amdgcn_s_setprio(1);
        #pragma unroll
        for (int kc = 0; kc < 4; ++kc) {
            bfrag pf = __builtin_bit_cast(bfrag, pfr[kc]);
            #pragma unroll
            for (int dt = 0; dt < 2; ++dt) {
                int row = dt*32 + l31, r7 = row & 7;
                bfrag vf = *(const bfrag*)(Vc + row*64 + ((kc*2 + hi) ^ r7)*8);
                oacc[dt] = __builtin_amdgcn_mfma_f32_32x32x16_bf16(pf, vf, oacc[dt], 0, 0, 0);
            }
            lfr = __builtin_amdgcn_mfma_f32_32x32x16_bf16(pf, vones, lfr, 0, 0, 0);
        }
        __builtin_amdgcn_s_setprio(0);
        __syncthreads();                   // drains prefetch vmcnt + frag reads
    }

    const int b = bh / HEADS, head = bh - b*HEADS;
    float* Op = Opart + (size_t)split * M_ * C_;
    float* lp = lpart + (size_t)split * (B_*HEADS) * N_;

    // lfr: every column (lane) holds l[q-row]; rows mapped like oacc
    if (l31 == 0) {
        #pragma unroll
        for (int r = 0; r < 16; ++r) {
            int n = q0 + w*32 + (r & 3) + 8*(r >> 2) + 4*hi;
            lp[bh*N_ + n] = lfr[r];
        }
    }

    #pragma unroll
    for (int dt = 0; dt < 2; ++dt)
        #pragma unroll
        for (int r = 0; r < 16; ++r) {
            int n = q0 + w*32 + (r & 3) + 8*(r >> 2) + 4*hi;
            int c = head*D_ + dt*32 + l31;
            Op[((size_t)b*N_ + n)*C_ + c] = oacc[dt][r];
        }
}

// ---------------------------------------------------------------------------
// Merge split-K partials: Ob = (sum_s O_s) / (sum_s l_s), bf16 out.
// ---------------------------------------------------------------------------
__global__ __launch_bounds__(256) void attn_merge(const float* __restrict__ Opart,
                                                  const float* __restrict__ lpart,
                                                  short* __restrict__ Ob) {
    int i = blockIdx.x * 256 + threadIdx.x;          // over M_*C_/4
    int m = i / (C_/4);
    int c = (i - m*(C_/4)) * 4;
    int b = m / N_, n = m - b*N_;
    int bh = b*HEADS + (c >> 6);
    float4 o0 = ((const float4*)Opart)[i];
    float4 o1 = ((const float4*)(Opart + (size_t)M_*C_))[i];
    float l = lpart[bh*N_ + n] + lpart[(B_*HEADS)*N_ + bh*N_ + n];
    float inv = 1.f / l;
    short4 o;
    o.x = f2bf((o0.x + o1.x) * inv);
    o.y = f2bf((o0.y + o1.y) * inv);
    o.z = f2bf((o0.z + o1.z) * inv);
    o.w = f2bf((o0.w + o1.w) * inv);
    ((short4*)Ob)[i] = o;
}

// ---------------------------------------------------------------------------
// Proj GEMM: out[m][f] = sum_c O[m][c]*w[f][c] + bias[f], fp32 out.
// ---------------------------------------------------------------------------
__global__ __launch_bounds__(256) void proj_gemm(const short* __restrict__ Ab,
                                                 const short* __restrict__ wb,
                                                 const float* __restrict__ bias,
                                                 float* __restrict__ out) {
    __shared__ short As[128*32];
    __shared__ short Bs[128*32];
    const int t = threadIdx.x;
    const int w = t >> 6, lane = t & 63;
    const int quad = lane >> 4, l15 = lane & 15;
    const int wr = w >> 1, wc = w & 1;
    const int m0 = blockIdx.y * 128, f0 = blockIdx.x * 128;

    ffrag acc[4][4] = {};

    for (int k0 = 0; k0 < C_; k0 += 32) {
        __syncthreads();
        #pragma unroll
        for (int r = 0; r < 2; ++r) {
            int seg = r*4 + w;
            int row = seg*16 + (lane >> 2);
            int kk  = (lane & 3) * 8;
            gl2lds16(Ab + (size_t)(m0+row)*C_ + k0 + kk, As + seg*512);
            gl2lds16(wb + (size_t)(f0+row)*C_ + k0 + kk, Bs + seg*512);
        }
        __syncthreads();
        bfrag af[4], bf[4];
        #pragma unroll
        for (int i = 0; i < 4; ++i)
            af[i] = *(const bfrag*)(As + (wr*64 + i*16 + l15)*32 + quad*8);
        #pragma unroll
        for (int j = 0; j < 4; ++j)
            bf[j] = *(const bfrag*)(Bs + (wc*64 + j*16 + l15)*32 + quad*8);
        #pragma unroll
        for (int i = 0; i < 4; ++i)
            #pragma unroll
            for (int j = 0; j < 4; ++j)
                acc[i][j] = __builtin_amdgcn_mfma_f32_16x16x32_bf16(af[i], bf[j], acc[i][j], 0, 0, 0);
    }

    #pragma unroll
    for (int i = 0; i < 4; ++i) {
        int mbase = m0 + wr*64 + i*16 + quad*4;
        #pragma unroll
        for (int j = 0; j < 4; ++j) {
            int f = f0 + wc*64 + j*16 + l15;
            float bv = bias[f];
            #pragma unroll
            for (int r = 0; r < 4; ++r)
                out[(size_t)(mbase + r)*C_ + f] = acc[i][j][r] + bv;
        }
    }
}

// ---------------------------------------------------------------------------
extern "C" void kernel_launch(void* const* d_in, const int* in_sizes, int n_in,
                              void* d_out, int out_size, void* d_ws, size_t ws_size,
                              hipStream_t stream) {
    const float* x      = (const float*)d_in[0];
    const float* qkv_w  = (const float*)d_in[3];
    const float* proj_w = (const float*)d_in[4];
    const float* proj_b = (const float*)d_in[5];
    float* out = (float*)d_out;

    const size_t nx = (size_t)M_ * C_;        // 3,538,944
    const size_t nq = (size_t)F3 * C_;        // 1,769,472
    const size_t np = (size_t)C_ * C_;        //   589,824
    short* xb  = (short*)d_ws;
    short* qwb = xb  + nx;
    short* pwb = qwb + nq;
    short* Qb  = pwb + np;
    short* Kb  = Qb  + nx;
    short* Vtb = Kb  + nx;
    short* Ob  = Vtb + nx;
    float* Opart = (float*)(Ob + nx);                       // SPLITS * M_*C_
    float* lpart = Opart + (size_t)SPLITS * M_ * C_;        // SPLITS * 24*N_

    const int ncast4 = (int)((nx + nq + np) / 4);
    cast_all<<<dim3((ncast4 + 255)/256), 256, 0, stream>>>(x, qkv_w, proj_w, xb);

    qkv_gemm<<<dim3(F3/128, M_/128), 256, 0, stream>>>(xb, qwb, Qb, Kb, Vtb);
    attn_mfma<<<dim3(B_*HEADS, N_/128, SPLITS), 256, 0, stream>>>(Qb, Kb, Vtb, Opart, lpart);
    attn_merge<<<dim3(((int)(nx/4) + 255)/256), 256, 0, stream>>>(Opart, lpart, Ob);
    proj_gemm<<<dim3(C_/128, M_/128), 256, 0, stream>>>(Ob, pwb, proj_b, out);
}

// Round 3
// 194.193 us; speedup vs baseline: 1.0997x; 1.0179x over previous
//
#include <hip/hip_runtime.h>

#define B_    2
#define N_    2304
#define C_    768
#define HEADS 12
#define D_    64
#define F3    2304
#define M_    (B_*N_)        // 4608
#define SPLITS 2
#define KSPAN (N_/SPLITS)    // 1152
// SCALE(0.125) * log2(e) folded into Q at qkv epilogue:
#define QSCALE 0.18033688011112042f

typedef __attribute__((ext_vector_type(8)))  short bfrag;    // 8 x bf16 (4 VGPR)
typedef __attribute__((ext_vector_type(4)))  float ffrag;    // 16x16 acc
typedef __attribute__((ext_vector_type(16))) float ffrag16;  // 32x32 acc
typedef __attribute__((ext_vector_type(4)))  unsigned ufrag; // 4 x b32 = 8 bf16
typedef __attribute__((ext_vector_type(2)))  unsigned uint2v;

__device__ __forceinline__ short f2bf(float f) {
    unsigned u = __float_as_uint(f);
    u += 0x7fff + ((u >> 16) & 1);          // RNE
    return (short)(u >> 16);
}

__device__ __forceinline__ void gl2lds16(const void* g, void* l) {
    __builtin_amdgcn_global_load_lds(
        (const __attribute__((address_space(1))) void*)g,
        (__attribute__((address_space(3))) void*)l, 16, 0, 0);
}

// trunc-pack two fp32 -> (bf16(a) low | bf16(b) high) in ONE v_perm_b32.
// bias-safe here because numerator (PV) and denominator (ones-MFMA) both
// consume the same truncated fragments -> common bias cancels in the ratio.
__device__ __forceinline__ unsigned pktrunc(float a, float b) {
    return __builtin_amdgcn_perm(__float_as_uint(a), __float_as_uint(b),
                                 0x03020706u);
}

// ---------------------------------------------------------------------------
// Fused fp32 -> bf16 cast of x, qkv_w, proj_w (dsts contiguous in ws).
// ---------------------------------------------------------------------------
__global__ __launch_bounds__(256) void cast_all(const float* __restrict__ x,
                                                const float* __restrict__ qw,
                                                const float* __restrict__ pw,
                                                short* __restrict__ dst) {
    const int nx4 = (M_*C_)/4, nq4 = (F3*C_)/4, np4 = (C_*C_)/4;
    int i = blockIdx.x * 256 + threadIdx.x;
    if (i >= nx4 + nq4 + np4) return;
    const float* src; int off;
    if (i < nx4)            { src = x;  off = i; }
    else if (i < nx4 + nq4) { src = qw; off = i - nx4; }
    else                    { src = pw; off = i - nx4 - nq4; }
    float4 v = ((const float4*)src)[off];
    short4 o;
    o.x = f2bf(v.x); o.y = f2bf(v.y); o.z = f2bf(v.z); o.w = f2bf(v.w);
    ((short4*)dst)[i] = o;
}

// ---------------------------------------------------------------------------
// QKV GEMM: qkv[m][f] = sum_c x[m][c]*w[f][c]  (NT), m97 structure
// + 2-phase double-buffered pipeline (prefetch K-step t+1 before compute of
//   t; ONE barrier per step — its vmcnt/lgkmcnt drain is the wait)
// + XCD-chunked blockIdx swizzle (648 blocks % 8 == 0 -> simple form is
//   bijective): each XCD's L2 keeps ~4.5 A-panels + all of B resident.
// Q stored pre-scaled by SCALE*log2e; V stored transposed [bh,d,n].
// ---------------------------------------------------------------------------
__global__ __launch_bounds__(256) void qkv_gemm(const short* __restrict__ xb,
                                                const short* __restrict__ wb,
                                                short* __restrict__ Qb,
                                                short* __restrict__ Kb,
                                                short* __restrict__ Vtb) {
    __shared__ short As[2][128*32];
    __shared__ short Bs[2][128*32];
    const int t = threadIdx.x;
    const int w = t >> 6, lane = t & 63;
    const int quad = lane >> 4, l15 = lane & 15;
    const int wr = w >> 1, wc = w & 1;

    const int nwg = gridDim.x * gridDim.y;
    const int bid = blockIdx.y * gridDim.x + blockIdx.x;
    const int swz = (bid & 7) * (nwg >> 3) + (bid >> 3);
    const int m0 = (swz / gridDim.x) * 128, f0 = (swz % gridDim.x) * 128;

    const int srow = lane >> 2;            // row within 16-row segment
    const int skk  = (lane & 3) * 8;       // bf16 offset within 32-col row

    ffrag acc[4][4] = {};

    // prologue: stage K-step 0 into buffer 0
    #pragma unroll
    for (int r = 0; r < 2; ++r) {
        int seg = r*4 + w;
        int row = seg*16 + srow;
        gl2lds16(xb + (size_t)(m0+row)*C_ + skk, As[0] + seg*512);
        gl2lds16(wb + (size_t)(f0+row)*C_ + skk, Bs[0] + seg*512);
    }
    __syncthreads();

    const int NKT = C_/32;                 // 24
    for (int kt = 0; kt < NKT; ++kt) {
        const int cur = kt & 1;
        if (kt + 1 < NKT) {                // prefetch next K-step into buf^1
            const int k0n = (kt+1)*32;
            #pragma unroll
            for (int r = 0; r < 2; ++r) {
                int seg = r*4 + w;
                int row = seg*16 + srow;
                gl2lds16(xb + (size_t)(m0+row)*C_ + k0n + skk, As[cur^1] + seg*512);
                gl2lds16(wb + (size_t)(f0+row)*C_ + k0n + skk, Bs[cur^1] + seg*512);
            }
        }
        bfrag af[4], bf[4];
        #pragma unroll
        for (int i = 0; i < 4; ++i)
            af[i] = *(const bfrag*)(As[cur] + (wr*64 + i*16 + l15)*32 + quad*8);
        #pragma unroll
        for (int j = 0; j < 4; ++j)
            bf[j] = *(const bfrag*)(Bs[cur] + (wc*64 + j*16 + l15)*32 + quad*8);
        #pragma unroll
        for (int i = 0; i < 4; ++i)
            #pragma unroll
            for (int j = 0; j < 4; ++j)
                acc[i][j] = __builtin_amdgcn_mfma_f32_16x16x32_bf16(af[i], bf[j], acc[i][j], 0, 0, 0);
        __syncthreads();                   // drains prefetch vmcnt + frag reads
    }

    const int b   = m0 / N_;
    const int seg = f0 + wc*64;
    const int which = seg / C_;                  // 0=Q 1=K 2=V
    const int head  = (seg - which*C_) >> 6;
    const int bh    = b*HEADS + head;
    const int nbase = (m0 - b*N_) + wr*64 + quad*4;

    if (which == 0) {
        #pragma unroll
        for (int i = 0; i < 4; ++i) {
            int n0 = nbase + i*16;
            #pragma unroll
            for (int j = 0; j < 4; ++j) {
                int d = j*16 + l15;
                #pragma unroll
                for (int r = 0; r < 4; ++r)
                    Qb[((size_t)bh*N_ + n0 + r)*D_ + d] = f2bf(acc[i][j][r] * QSCALE);
            }
        }
    } else if (which == 1) {
        #pragma unroll
        for (int i = 0; i < 4; ++i) {
            int n0 = nbase + i*16;
            #pragma unroll
            for (int j = 0; j < 4; ++j) {
                int d = j*16 + l15;
                #pragma unroll
                for (int r = 0; r < 4; ++r)
                    Kb[((size_t)bh*N_ + n0 + r)*D_ + d] = f2bf(acc[i][j][r]);
            }
        }
    } else {
        #pragma unroll
        for (int i = 0; i < 4; ++i) {
            int n0 = nbase + i*16;
            #pragma unroll
            for (int j = 0; j < 4; ++j) {
                int d = j*16 + l15;
                short4 vv;
                vv.x = f2bf(acc[i][j][0]);
                vv.y = f2bf(acc[i][j][1]);
                vv.z = f2bf(acc[i][j][2]);
                vv.w = f2bf(acc[i][j][3]);
                *(short4*)(Vtb + ((size_t)bh*D_ + d)*N_ + n0) = vv;
            }
        }
    }
}

// ---------------------------------------------------------------------------
// Flash attention, 32x32x16 bf16 MFMA, no-max softmax, split-K over grid.z.
// 4-wave blocks over 128 q-rows (K/V staged once per block), K/V LDS
// double-buffered with a 2-phase pipeline. Q tile (16 KiB) overlays buffer
// set 1 during the prologue only. P transpose via v_permlane32_swap_b32.
// Grid (B*H, N/128, SPLITS). Block 256 thr (4 waves), wave w: q-rows
// w*32..w*32+31 of the 128-row tile.
// LDS rows 128B, XOR-swizzled: chunk c of row r lives at (c ^ (r&7))*16B.
// 32x32 C layout: col = lane&31, row = (reg&3) + 8*(reg>>2) + 4*(lane>>5).
// ---------------------------------------------------------------------------
__global__ __launch_bounds__(256, 4) void attn_mfma(const short* __restrict__ Qb,
                                                    const short* __restrict__ Kb,
                                                    const short* __restrict__ Vtb,
                                                    float* __restrict__ Opart,
                                                    float* __restrict__ lpart) {
    // 32 KiB total: set s at lds + s*8192 shorts (K 4096 | V 4096).
    __shared__ short lds[16384];
    const int t = threadIdx.x;
    const int w = t >> 6, lane = t & 63;
    const int l31 = lane & 31, hi = lane >> 5;
    const int bh = blockIdx.x, q0 = blockIdx.y * 128;
    const int split = blockIdx.z;
    const int kbase = split * KSPAN;
    const size_t base = (size_t)bh * N_ * D_;
    const int lrow = lane >> 3;            // row within 8-row segment
    const int lc   = (lane & 7) ^ lrow;    // swizzled source chunk

    short* Qs = lds + 8192;                // overlays set 1

    // prologue: stage Q tile (128 x 64) into set1 region, K/V tile 0 into set0
    #pragma unroll
    for (int r = 0; r < 4; ++r) {
        int s = r*4 + w;
        gl2lds16(Qb + base + (size_t)(q0 + s*8 + lrow)*D_ + lc*8, Qs + s*512);
    }
    #pragma unroll
    for (int r = 0; r < 2; ++r) {
        int s = r*4 + w;
        int row = s*8 + lrow;
        gl2lds16(Kb  + base + (size_t)(kbase+row)*D_ + lc*8,    lds + s*512);
        gl2lds16(Vtb + (size_t)(bh*D_ + row)*N_ + kbase + lc*8, lds + 4096 + s*512);
    }
    __syncthreads();                       // Q + tile0 staged

    // hoist Q B-frags (loop-invariant)
    bfrag qf[4];
    {
        int row = w*32 + l31, r7 = row & 7;
        #pragma unroll
        for (int kc = 0; kc < 4; ++kc)
            qf[kc] = *(const bfrag*)(Qs + row*64 + ((kc*2 + hi) ^ r7)*8);
    }
    __syncthreads();                       // Q-frag reads done before set1 reuse

    // ones B-frag for the l (row-sum) MFMA
    bfrag vones;
    #pragma unroll
    for (int j = 0; j < 8; ++j) vones[j] = (short)0x3f80;

    ffrag16 oacc[2], lfr;
    #pragma unroll
    for (int r = 0; r < 16; ++r) { oacc[0][r] = 0.f; oacc[1][r] = 0.f; lfr[r] = 0.f; }

    const int NT = KSPAN / 64;             // 18
    for (int ti = 0; ti < NT; ++ti) {
        const int cur = ti & 1;
        const short* Kc = lds + cur*8192;
        const short* Vc = Kc + 4096;

        // issue next tile's staging into the other buffer set (hidden under
        // this tile's compute; drained by the trailing barrier)
        if (ti + 1 < NT) {
            short* Kn = lds + (cur^1)*8192;
            const int k0n = kbase + (ti+1)*64;
            #pragma unroll
            for (int r = 0; r < 2; ++r) {
                int s = r*4 + w;
                int row = s*8 + lrow;
                gl2lds16(Kb  + base + (size_t)(k0n+row)*D_ + lc*8,    Kn + s*512);
                gl2lds16(Vtb + (size_t)(bh*D_ + row)*N_ + k0n + lc*8, Kn + 4096 + s*512);
            }
        }

        ufrag pfr[4];                      // A-frags for PV, kc = kt*2 + {lo,hi}
        #pragma unroll
        for (int kt = 0; kt < 2; ++kt) {
            // S^T tile: rows k (reg-dist), cols q (lane)
            ffrag16 s;
            #pragma unroll
            for (int r = 0; r < 16; ++r) s[r] = 0.f;
            int row = kt*32 + l31, r7 = row & 7;
            __builtin_amdgcn_s_setprio(1);
            #pragma unroll
            for (int kc = 0; kc < 4; ++kc) {
                bfrag kf = *(const bfrag*)(Kc + row*64 + ((kc*2 + hi) ^ r7)*8);
                s = __builtin_amdgcn_mfma_f32_32x32x16_bf16(kf, qf[kc], s, 0, 0, 0);
            }
            __builtin_amdgcn_s_setprio(0);
            // p = 2^s; trunc-pack to bf16 pairs (k even-adjacent)
            #pragma unroll
            for (int r = 0; r < 16; ++r)
                s[r] = __builtin_amdgcn_exp2f(s[r]);
            // group g (regs 4g..4g+3) holds k_local = 8g + 4hi + {0..3}
            unsigned q01_0 = pktrunc(s[0],  s[1]),  q23_0 = pktrunc(s[2],  s[3]);
            unsigned q01_1 = pktrunc(s[4],  s[5]),  q23_1 = pktrunc(s[6],  s[7]);
            unsigned q01_2 = pktrunc(s[8],  s[9]),  q23_2 = pktrunc(s[10], s[11]);
            unsigned q01_3 = pktrunc(s[12], s[13]), q23_3 = pktrunc(s[14], s[15]);
            // v_permlane32_swap: {a',b'} with a' = [a.lo32 | b.lo32],
            // b' = [a.hi32 | b.hi32] — exactly the lo/hi fragment exchange.
            uint2v e0 = __builtin_amdgcn_permlane32_swap(q01_0, q01_1, false, false);
            uint2v e1 = __builtin_amdgcn_permlane32_swap(q23_0, q23_1, false, false);
            uint2v e2 = __builtin_amdgcn_permlane32_swap(q01_2, q01_3, false, false);
            uint2v e3 = __builtin_amdgcn_permlane32_swap(q23_2, q23_3, false, false);
            ufrag lo, hif;
            lo[0]  = e0[0]; lo[1]  = e1[0]; lo[2]  = e0[1]; lo[3]  = e1[1];
            hif[0] = e2[0]; hif[1] = e3[0]; hif[2] = e2[1]; hif[3] = e3[1];
            pfr[kt*2]     = lo;            // k_local 0-15  (P[q][8hi+j] form)
            pfr[kt*2 + 1] = hif;           // k_local 16-31
        }

        // O += P V ; l += P 1  (consumes the same truncated P frags)
        __builtin_amdgcn_s_setprio(1);
        #pragma unroll
        for (int kc = 0; kc < 4; ++kc) {
            bfrag pf = __builtin_bit_cast(bfrag, pfr[kc]);
            #pragma unroll
            for (int dt = 0; dt < 2; ++dt) {
                int row = dt*32 + l31, r7 = row & 7;
                bfrag vf = *(const bfrag*)(Vc + row*64 + ((kc*2 + hi) ^ r7)*8);
                oacc[dt] = __builtin_amdgcn_mfma_f32_32x32x16_bf16(pf, vf, oacc[dt], 0, 0, 0);
            }
            lfr = __builtin_amdgcn_mfma_f32_32x32x16_bf16(pf, vones, lfr, 0, 0, 0);
        }
        __builtin_amdgcn_s_setprio(0);
        __syncthreads();                   // drains prefetch vmcnt + frag reads
    }

    const int b = bh / HEADS, head = bh - b*HEADS;
    float* Op = Opart + (size_t)split * M_ * C_;
    float* lp = lpart + (size_t)split * (B_*HEADS) * N_;

    // lfr: every column (lane) holds l[q-row]; rows mapped like oacc
    if (l31 == 0) {
        #pragma unroll
        for (int r = 0; r < 16; ++r) {
            int n = q0 + w*32 + (r & 3) + 8*(r >> 2) + 4*hi;
            lp[bh*N_ + n] = lfr[r];
        }
    }

    #pragma unroll
    for (int dt = 0; dt < 2; ++dt)
        #pragma unroll
        for (int r = 0; r < 16; ++r) {
            int n = q0 + w*32 + (r & 3) + 8*(r >> 2) + 4*hi;
            int c = head*D_ + dt*32 + l31;
            Op[((size_t)b*N_ + n)*C_ + c] = oacc[dt][r];
        }
}

// ---------------------------------------------------------------------------
// Merge split-K partials: Ob = (sum_s O_s) / (sum_s l_s), bf16 out.
// ---------------------------------------------------------------------------
__global__ __launch_bounds__(256) void attn_merge(const float* __restrict__ Opart,
                                                  const float* __restrict__ lpart,
                                                  short* __restrict__ Ob) {
    int i = blockIdx.x * 256 + threadIdx.x;          // over M_*C_/4
    int m = i / (C_/4);
    int c = (i - m*(C_/4)) * 4;
    int b = m / N_, n = m - b*N_;
    int bh = b*HEADS + (c >> 6);
    float4 o0 = ((const float4*)Opart)[i];
    float4 o1 = ((const float4*)(Opart + (size_t)M_*C_))[i];
    float l = lpart[bh*N_ + n] + lpart[(B_*HEADS)*N_ + bh*N_ + n];
    float inv = 1.f / l;
    short4 o;
    o.x = f2bf((o0.x + o1.x) * inv);
    o.y = f2bf((o0.y + o1.y) * inv);
    o.z = f2bf((o0.z + o1.z) * inv);
    o.w = f2bf((o0.w + o1.w) * inv);
    ((short4*)Ob)[i] = o;
}

// ---------------------------------------------------------------------------
// Proj GEMM: out[m][f] = sum_c O[m][c]*w[f][c] + bias[f], fp32 out.
// Same 2-phase pipeline + XCD swizzle (216 blocks % 8 == 0).
// ---------------------------------------------------------------------------
__global__ __launch_bounds__(256) void proj_gemm(const short* __restrict__ Ab,
                                                 const short* __restrict__ wb,
                                                 const float* __restrict__ bias,
                                                 float* __restrict__ out) {
    __shared__ short As[2][128*32];
    __shared__ short Bs[2][128*32];
    const int t = threadIdx.x;
    const int w = t >> 6, lane = t & 63;
    const int quad = lane >> 4, l15 = lane & 15;
    const int wr = w >> 1, wc = w & 1;

    const int nwg = gridDim.x * gridDim.y;
    const int bid = blockIdx.y * gridDim.x + blockIdx.x;
    const int swz = (bid & 7) * (nwg >> 3) + (bid >> 3);
    const int m0 = (swz / gridDim.x) * 128, f0 = (swz % gridDim.x) * 128;

    const int srow = lane >> 2;
    const int skk  = (lane & 3) * 8;

    ffrag acc[4][4] = {};

    // prologue: stage K-step 0 into buffer 0
    #pragma unroll
    for (int r = 0; r < 2; ++r) {
        int seg = r*4 + w;
        int row = seg*16 + srow;
        gl2lds16(Ab + (size_t)(m0+row)*C_ + skk, As[0] + seg*512);
        gl2lds16(wb + (size_t)(f0+row)*C_ + skk, Bs[0] + seg*512);
    }
    __syncthreads();

    const int NKT = C_/32;                 // 24
    for (int kt = 0; kt < NKT; ++kt) {
        const int cur = kt & 1;
        if (kt + 1 < NKT) {
            const int k0n = (kt+1)*32;
            #pragma unroll
            for (int r = 0; r < 2; ++r) {
                int seg = r*4 + w;
                int row = seg*16 + srow;
                gl2lds16(Ab + (size_t)(m0+row)*C_ + k0n + skk, As[cur^1] + seg*512);
                gl2lds16(wb + (size_t)(f0+row)*C_ + k0n + skk, Bs[cur^1] + seg*512);
            }
        }
        bfrag af[4], bf[4];
        #pragma unroll
        for (int i = 0; i < 4; ++i)
            af[i] = *(const bfrag*)(As[cur] + (wr*64 + i*16 + l15)*32 + quad*8);
        #pragma unroll
        for (int j = 0; j < 4; ++j)
            bf[j] = *(const bfrag*)(Bs[cur] + (wc*64 + j*16 + l15)*32 + quad*8);
        #pragma unroll
        for (int i = 0; i < 4; ++i)
            #pragma unroll
            for (int j = 0; j < 4; ++j)
                acc[i][j] = __builtin_amdgcn_mfma_f32_16x16x32_bf16(af[i], bf[j], acc[i][j], 0, 0, 0);
        __syncthreads();
    }

    #pragma unroll
    for (int i = 0; i < 4; ++i) {
        int mbase = m0 + wr*64 + i*16 + quad*4;
        #pragma unroll
        for (int j = 0; j < 4; ++j) {
            int f = f0 + wc*64 + j*16 + l15;
            float bv = bias[f];
            #pragma unroll
            for (int r = 0; r < 4; ++r)
                out[(size_t)(mbase + r)*C_ + f] = acc[i][j][r] + bv;
        }
    }
}

// ---------------------------------------------------------------------------
extern "C" void kernel_launch(void* const* d_in, const int* in_sizes, int n_in,
                              void* d_out, int out_size, void* d_ws, size_t ws_size,
                              hipStream_t stream) {
    const float* x      = (const float*)d_in[0];
    const float* qkv_w  = (const float*)d_in[3];
    const float* proj_w = (const float*)d_in[4];
    const float* proj_b = (const float*)d_in[5];
    float* out = (float*)d_out;

    const size_t nx = (size_t)M_ * C_;        // 3,538,944
    const size_t nq = (size_t)F3 * C_;        // 1,769,472
    const size_t np = (size_t)C_ * C_;        //   589,824
    short* xb  = (short*)d_ws;
    short* qwb = xb  + nx;
    short* pwb = qwb + nq;
    short* Qb  = pwb + np;
    short* Kb  = Qb  + nx;
    short* Vtb = Kb  + nx;
    short* Ob  = Vtb + nx;
    float* Opart = (float*)(Ob + nx);                       // SPLITS * M_*C_
    float* lpart = Opart + (size_t)SPLITS * M_ * C_;        // SPLITS * 24*N_

    const int ncast4 = (int)((nx + nq + np) / 4);
    cast_all<<<dim3((ncast4 + 255)/256), 256, 0, stream>>>(x, qkv_w, proj_w, xb);

    qkv_gemm<<<dim3(F3/128, M_/128), 256, 0, stream>>>(xb, qwb, Qb, Kb, Vtb);
    attn_mfma<<<dim3(B_*HEADS, N_/128, SPLITS), 256, 0, stream>>>(Qb, Kb, Vtb, Opart, lpart);
    attn_merge<<<dim3(((int)(nx/4) + 255)/256), 256, 0, stream>>>(Opart, lpart, Ob);
    proj_gemm<<<dim3(C_/128, M_/128), 256, 0, stream>>>(Ob, pwb, proj_b, out);
}

// Round 4
// 194.020 us; speedup vs baseline: 1.1007x; 1.0009x over previous
//
#include <hip/hip_runtime.h>

#define B_    2
#define N_    2304
#define C_    768
#define HEADS 12
#define D_    64
#define F3    2304
#define M_    (B_*N_)        // 4608
#define SPLITS 3
#define KSPAN (N_/SPLITS)    // 768
// SCALE(0.125) * log2(e) folded into Q at qkv epilogue:
#define QSCALE 0.18033688011112042f

typedef __attribute__((ext_vector_type(8)))  short bfrag;    // 8 x bf16 (4 VGPR)
typedef __attribute__((ext_vector_type(4)))  float ffrag;    // 16x16 acc
typedef __attribute__((ext_vector_type(16))) float ffrag16;  // 32x32 acc
typedef __attribute__((ext_vector_type(4)))  unsigned ufrag; // 4 x b32 = 8 bf16
typedef __attribute__((ext_vector_type(2)))  unsigned uint2v;

__device__ __forceinline__ short f2bf(float f) {
    unsigned u = __float_as_uint(f);
    u += 0x7fff + ((u >> 16) & 1);          // RNE
    return (short)(u >> 16);
}

__device__ __forceinline__ void gl2lds16(const void* g, void* l) {
    __builtin_amdgcn_global_load_lds(
        (const __attribute__((address_space(1))) void*)g,
        (__attribute__((address_space(3))) void*)l, 16, 0, 0);
}

// trunc-pack two fp32 -> (bf16(a) low | bf16(b) high) in ONE v_perm_b32.
// bias-safe here because numerator (PV) and denominator (l sum) both
// consume the same truncated values -> common bias cancels in the ratio.
__device__ __forceinline__ unsigned pktrunc(float a, float b) {
    return __builtin_amdgcn_perm(__float_as_uint(a), __float_as_uint(b),
                                 0x03020706u);
}

// exactly the bf16 value pktrunc keeps (bit truncation): for the l sum.
__device__ __forceinline__ float btrunc(float a) {
    return __uint_as_float(__float_as_uint(a) & 0xffff0000u);
}

// ---------------------------------------------------------------------------
// Fused fp32 -> bf16 cast of x, qkv_w, proj_w (dsts contiguous in ws).
// ---------------------------------------------------------------------------
__global__ __launch_bounds__(256) void cast_all(const float* __restrict__ x,
                                                const float* __restrict__ qw,
                                                const float* __restrict__ pw,
                                                short* __restrict__ dst) {
    const int nx4 = (M_*C_)/4, nq4 = (F3*C_)/4, np4 = (C_*C_)/4;
    int i = blockIdx.x * 256 + threadIdx.x;
    if (i >= nx4 + nq4 + np4) return;
    const float* src; int off;
    if (i < nx4)            { src = x;  off = i; }
    else if (i < nx4 + nq4) { src = qw; off = i - nx4; }
    else                    { src = pw; off = i - nx4 - nq4; }
    float4 v = ((const float4*)src)[off];
    short4 o;
    o.x = f2bf(v.x); o.y = f2bf(v.y); o.z = f2bf(v.z); o.w = f2bf(v.w);
    ((short4*)dst)[i] = o;
}

// ---------------------------------------------------------------------------
// QKV GEMM: qkv[m][f] = sum_c x[m][c]*w[f][c]  (NT), m97 structure
// + 2-phase double-buffered pipeline (prefetch K-step t+1 before compute of
//   t; ONE barrier per step — its vmcnt/lgkmcnt drain is the wait)
// + XCD-chunked blockIdx swizzle (648 blocks % 8 == 0 -> simple form is
//   bijective): each XCD's L2 keeps ~4.5 A-panels + all of B resident.
// Q stored pre-scaled by SCALE*log2e; V stored transposed [bh,d,n].
// ---------------------------------------------------------------------------
__global__ __launch_bounds__(256) void qkv_gemm(const short* __restrict__ xb,
                                                const short* __restrict__ wb,
                                                short* __restrict__ Qb,
                                                short* __restrict__ Kb,
                                                short* __restrict__ Vtb) {
    __shared__ short As[2][128*32];
    __shared__ short Bs[2][128*32];
    const int t = threadIdx.x;
    const int w = t >> 6, lane = t & 63;
    const int quad = lane >> 4, l15 = lane & 15;
    const int wr = w >> 1, wc = w & 1;

    const int nwg = gridDim.x * gridDim.y;
    const int bid = blockIdx.y * gridDim.x + blockIdx.x;
    const int swz = (bid & 7) * (nwg >> 3) + (bid >> 3);
    const int m0 = (swz / gridDim.x) * 128, f0 = (swz % gridDim.x) * 128;

    const int srow = lane >> 2;            // row within 16-row segment
    const int skk  = (lane & 3) * 8;       // bf16 offset within 32-col row

    ffrag acc[4][4] = {};

    // prologue: stage K-step 0 into buffer 0
    #pragma unroll
    for (int r = 0; r < 2; ++r) {
        int seg = r*4 + w;
        int row = seg*16 + srow;
        gl2lds16(xb + (size_t)(m0+row)*C_ + skk, As[0] + seg*512);
        gl2lds16(wb + (size_t)(f0+row)*C_ + skk, Bs[0] + seg*512);
    }
    __syncthreads();

    const int NKT = C_/32;                 // 24
    for (int kt = 0; kt < NKT; ++kt) {
        const int cur = kt & 1;
        if (kt + 1 < NKT) {                // prefetch next K-step into buf^1
            const int k0n = (kt+1)*32;
            #pragma unroll
            for (int r = 0; r < 2; ++r) {
                int seg = r*4 + w;
                int row = seg*16 + srow;
                gl2lds16(xb + (size_t)(m0+row)*C_ + k0n + skk, As[cur^1] + seg*512);
                gl2lds16(wb + (size_t)(f0+row)*C_ + k0n + skk, Bs[cur^1] + seg*512);
            }
        }
        bfrag af[4], bf[4];
        #pragma unroll
        for (int i = 0; i < 4; ++i)
            af[i] = *(const bfrag*)(As[cur] + (wr*64 + i*16 + l15)*32 + quad*8);
        #pragma unroll
        for (int j = 0; j < 4; ++j)
            bf[j] = *(const bfrag*)(Bs[cur] + (wc*64 + j*16 + l15)*32 + quad*8);
        #pragma unroll
        for (int i = 0; i < 4; ++i)
            #pragma unroll
            for (int j = 0; j < 4; ++j)
                acc[i][j] = __builtin_amdgcn_mfma_f32_16x16x32_bf16(af[i], bf[j], acc[i][j], 0, 0, 0);
        __syncthreads();                   // drains prefetch vmcnt + frag reads
    }

    const int b   = m0 / N_;
    const int seg = f0 + wc*64;
    const int which = seg / C_;                  // 0=Q 1=K 2=V
    const int head  = (seg - which*C_) >> 6;
    const int bh    = b*HEADS + head;
    const int nbase = (m0 - b*N_) + wr*64 + quad*4;

    if (which == 0) {
        #pragma unroll
        for (int i = 0; i < 4; ++i) {
            int n0 = nbase + i*16;
            #pragma unroll
            for (int j = 0; j < 4; ++j) {
                int d = j*16 + l15;
                #pragma unroll
                for (int r = 0; r < 4; ++r)
                    Qb[((size_t)bh*N_ + n0 + r)*D_ + d] = f2bf(acc[i][j][r] * QSCALE);
            }
        }
    } else if (which == 1) {
        #pragma unroll
        for (int i = 0; i < 4; ++i) {
            int n0 = nbase + i*16;
            #pragma unroll
            for (int j = 0; j < 4; ++j) {
                int d = j*16 + l15;
                #pragma unroll
                for (int r = 0; r < 4; ++r)
                    Kb[((size_t)bh*N_ + n0 + r)*D_ + d] = f2bf(acc[i][j][r]);
            }
        }
    } else {
        #pragma unroll
        for (int i = 0; i < 4; ++i) {
            int n0 = nbase + i*16;
            #pragma unroll
            for (int j = 0; j < 4; ++j) {
                int d = j*16 + l15;
                short4 vv;
                vv.x = f2bf(acc[i][j][0]);
                vv.y = f2bf(acc[i][j][1]);
                vv.z = f2bf(acc[i][j][2]);
                vv.w = f2bf(acc[i][j][3]);
                *(short4*)(Vtb + ((size_t)bh*D_ + d)*N_ + n0) = vv;
            }
        }
    }
}

// ---------------------------------------------------------------------------
// Flash attention, 32x32x16 bf16 MFMA, no-max softmax, split-K over grid.z.
// 4-wave blocks over 128 q-rows; K/V LDS double-buffered, 2-phase pipeline.
// SPLITS=3 so grid = 1296 blocks = 5.06 blocks/CU, matching the 5-block LDS
// cap (32 KiB) -> ~20 resident waves/CU instead of 13.5 (occupancy lever).
// l (softmax denom) computed by per-lane VALU sum of the BIT-TRUNCATED
// exp values (exactly what the PV MFMA consumes -> bias cancels in O/l);
// this removes the 4 ones-MFMAs/iter (-20% MFMA work). Cross-half combine
// is one shfl_xor(32) at epilogue.
// P transpose via v_permlane32_swap_b32. Grid (B*H, N/128, SPLITS).
// LDS rows 128B, XOR-swizzled: chunk c of row r lives at (c ^ (r&7))*16B.
// 32x32 C layout: col = lane&31, row = (reg&3) + 8*(reg>>2) + 4*(lane>>5).
// ---------------------------------------------------------------------------
__global__ __launch_bounds__(256, 4) void attn_mfma(const short* __restrict__ Qb,
                                                    const short* __restrict__ Kb,
                                                    const short* __restrict__ Vtb,
                                                    float* __restrict__ Opart,
                                                    float* __restrict__ lpart) {
    // 32 KiB total: set s at lds + s*8192 shorts (K 4096 | V 4096).
    __shared__ short lds[16384];
    const int t = threadIdx.x;
    const int w = t >> 6, lane = t & 63;
    const int l31 = lane & 31, hi = lane >> 5;
    const int bh = blockIdx.x, q0 = blockIdx.y * 128;
    const int split = blockIdx.z;
    const int kbase = split * KSPAN;
    const size_t base = (size_t)bh * N_ * D_;
    const int lrow = lane >> 3;            // row within 8-row segment
    const int lc   = (lane & 7) ^ lrow;    // swizzled source chunk

    short* Qs = lds + 8192;                // overlays set 1

    // prologue: stage Q tile (128 x 64) into set1 region, K/V tile 0 into set0
    #pragma unroll
    for (int r = 0; r < 4; ++r) {
        int s = r*4 + w;
        gl2lds16(Qb + base + (size_t)(q0 + s*8 + lrow)*D_ + lc*8, Qs + s*512);
    }
    #pragma unroll
    for (int r = 0; r < 2; ++r) {
        int s = r*4 + w;
        int row = s*8 + lrow;
        gl2lds16(Kb  + base + (size_t)(kbase+row)*D_ + lc*8,    lds + s*512);
        gl2lds16(Vtb + (size_t)(bh*D_ + row)*N_ + kbase + lc*8, lds + 4096 + s*512);
    }
    __syncthreads();                       // Q + tile0 staged

    // hoist Q B-frags (loop-invariant)
    bfrag qf[4];
    {
        int row = w*32 + l31, r7 = row & 7;
        #pragma unroll
        for (int kc = 0; kc < 4; ++kc)
            qf[kc] = *(const bfrag*)(Qs + row*64 + ((kc*2 + hi) ^ r7)*8);
    }
    __syncthreads();                       // Q-frag reads done before set1 reuse

    ffrag16 oacc[2];
    #pragma unroll
    for (int r = 0; r < 16; ++r) { oacc[0][r] = 0.f; oacc[1][r] = 0.f; }
    float llane = 0.f;                     // softmax denom partial (this half)

    const int NT = KSPAN / 64;             // 12
    for (int ti = 0; ti < NT; ++ti) {
        const int cur = ti & 1;
        const short* Kc = lds + cur*8192;
        const short* Vc = Kc + 4096;

        // issue next tile's staging into the other buffer set (hidden under
        // this tile's compute; drained by the trailing barrier)
        if (ti + 1 < NT) {
            short* Kn = lds + (cur^1)*8192;
            const int k0n = kbase + (ti+1)*64;
            #pragma unroll
            for (int r = 0; r < 2; ++r) {
                int s = r*4 + w;
                int row = s*8 + lrow;
                gl2lds16(Kb  + base + (size_t)(k0n+row)*D_ + lc*8,    Kn + s*512);
                gl2lds16(Vtb + (size_t)(bh*D_ + row)*N_ + k0n + lc*8, Kn + 4096 + s*512);
            }
        }

        ufrag pfr[4];                      // A-frags for PV, kc = kt*2 + {lo,hi}
        #pragma unroll
        for (int kt = 0; kt < 2; ++kt) {
            // S^T tile: rows k (reg-dist), cols q (lane)
            ffrag16 s;
            #pragma unroll
            for (int r = 0; r < 16; ++r) s[r] = 0.f;
            int row = kt*32 + l31, r7 = row & 7;
            __builtin_amdgcn_s_setprio(1);
            #pragma unroll
            for (int kc = 0; kc < 4; ++kc) {
                bfrag kf = *(const bfrag*)(Kc + row*64 + ((kc*2 + hi) ^ r7)*8);
                s = __builtin_amdgcn_mfma_f32_32x32x16_bf16(kf, qf[kc], s, 0, 0, 0);
            }
            __builtin_amdgcn_s_setprio(0);
            // p = 2^s; trunc-pack to bf16 pairs (k even-adjacent)
            #pragma unroll
            for (int r = 0; r < 16; ++r)
                s[r] = __builtin_amdgcn_exp2f(s[r]);
            // l partial: sum of truncated values this lane holds (16 k's of
            // this lane's q column) — replaces the ones-MFMA.
            {
                float t0 = 0.f, t1 = 0.f;
                #pragma unroll
                for (int r = 0; r < 16; r += 2) {
                    t0 += btrunc(s[r]);
                    t1 += btrunc(s[r+1]);
                }
                llane += t0 + t1;
            }
            // group g (regs 4g..4g+3) holds k_local = 8g + 4hi + {0..3}
            unsigned q01_0 = pktrunc(s[0],  s[1]),  q23_0 = pktrunc(s[2],  s[3]);
            unsigned q01_1 = pktrunc(s[4],  s[5]),  q23_1 = pktrunc(s[6],  s[7]);
            unsigned q01_2 = pktrunc(s[8],  s[9]),  q23_2 = pktrunc(s[10], s[11]);
            unsigned q01_3 = pktrunc(s[12], s[13]), q23_3 = pktrunc(s[14], s[15]);
            // v_permlane32_swap: {a',b'} with a' = [a.lo32 | b.lo32],
            // b' = [a.hi32 | b.hi32] — exactly the lo/hi fragment exchange.
            uint2v e0 = __builtin_amdgcn_permlane32_swap(q01_0, q01_1, false, false);
            uint2v e1 = __builtin_amdgcn_permlane32_swap(q23_0, q23_1, false, false);
            uint2v e2 = __builtin_amdgcn_permlane32_swap(q01_2, q01_3, false, false);
            uint2v e3 = __builtin_amdgcn_permlane32_swap(q23_2, q23_3, false, false);
            ufrag lo, hif;
            lo[0]  = e0[0]; lo[1]  = e1[0]; lo[2]  = e0[1]; lo[3]  = e1[1];
            hif[0] = e2[0]; hif[1] = e3[0]; hif[2] = e2[1]; hif[3] = e3[1];
            pfr[kt*2]     = lo;            // k_local 0-15  (P[q][8hi+j] form)
            pfr[kt*2 + 1] = hif;           // k_local 16-31
        }

        // O += P V  (consumes the same truncated P frags as the l sum)
        __builtin_amdgcn_s_setprio(1);
        #pragma unroll
        for (int kc = 0; kc < 4; ++kc) {
            bfrag pf = __builtin_bit_cast(bfrag, pfr[kc]);
            #pragma unroll
            for (int dt = 0; dt < 2; ++dt) {
                int row = dt*32 + l31, r7 = row & 7;
                bfrag vf = *(const bfrag*)(Vc + row*64 + ((kc*2 + hi) ^ r7)*8);
                oacc[dt] = __builtin_amdgcn_mfma_f32_32x32x16_bf16(pf, vf, oacc[dt], 0, 0, 0);
            }
        }
        __builtin_amdgcn_s_setprio(0);
        __syncthreads();                   // drains prefetch vmcnt + frag reads
    }

    const int b = bh / HEADS, head = bh - b*HEADS;
    float* Op = Opart + (size_t)split * M_ * C_;
    float* lp = lpart + (size_t)split * (B_*HEADS) * N_;

    // combine the two 16-k halves of l (partner lane has same q, other hi)
    {
        float lpart_other = __shfl_xor(llane, 32, 64);
        float ltot = llane + lpart_other;
        if (hi == 0)
            lp[bh*N_ + q0 + w*32 + l31] = ltot;
    }

    #pragma unroll
    for (int dt = 0; dt < 2; ++dt)
        #pragma unroll
        for (int r = 0; r < 16; ++r) {
            int n = q0 + w*32 + (r & 3) + 8*(r >> 2) + 4*hi;
            int c = head*D_ + dt*32 + l31;
            Op[((size_t)b*N_ + n)*C_ + c] = oacc[dt][r];
        }
}

// ---------------------------------------------------------------------------
// Merge split-K partials: Ob = (sum_s O_s) / (sum_s l_s), bf16 out.
// ---------------------------------------------------------------------------
__global__ __launch_bounds__(256) void attn_merge(const float* __restrict__ Opart,
                                                  const float* __restrict__ lpart,
                                                  short* __restrict__ Ob) {
    int i = blockIdx.x * 256 + threadIdx.x;          // over M_*C_/4
    int m = i / (C_/4);
    int c = (i - m*(C_/4)) * 4;
    int b = m / N_, n = m - b*N_;
    int bh = b*HEADS + (c >> 6);
    const int LP = (B_*HEADS)*N_;
    float4 o0 = ((const float4*)Opart)[i];
    float4 o1 = ((const float4*)(Opart + (size_t)M_*C_))[i];
    float4 o2 = ((const float4*)(Opart + 2*(size_t)M_*C_))[i];
    float l = lpart[bh*N_ + n] + lpart[LP + bh*N_ + n] + lpart[2*LP + bh*N_ + n];
    float inv = 1.f / l;
    short4 o;
    o.x = f2bf((o0.x + o1.x + o2.x) * inv);
    o.y = f2bf((o0.y + o1.y + o2.y) * inv);
    o.z = f2bf((o0.z + o1.z + o2.z) * inv);
    o.w = f2bf((o0.w + o1.w + o2.w) * inv);
    ((short4*)Ob)[i] = o;
}

// ---------------------------------------------------------------------------
// Proj GEMM: out[m][f] = sum_c O[m][c]*w[f][c] + bias[f], fp32 out.
// Same 2-phase pipeline + XCD swizzle (216 blocks % 8 == 0).
// ---------------------------------------------------------------------------
__global__ __launch_bounds__(256) void proj_gemm(const short* __restrict__ Ab,
                                                 const short* __restrict__ wb,
                                                 const float* __restrict__ bias,
                                                 float* __restrict__ out) {
    __shared__ short As[2][128*32];
    __shared__ short Bs[2][128*32];
    const int t = threadIdx.x;
    const int w = t >> 6, lane = t & 63;
    const int quad = lane >> 4, l15 = lane & 15;
    const int wr = w >> 1, wc = w & 1;

    const int nwg = gridDim.x * gridDim.y;
    const int bid = blockIdx.y * gridDim.x + blockIdx.x;
    const int swz = (bid & 7) * (nwg >> 3) + (bid >> 3);
    const int m0 = (swz / gridDim.x) * 128, f0 = (swz % gridDim.x) * 128;

    const int srow = lane >> 2;
    const int skk  = (lane & 3) * 8;

    ffrag acc[4][4] = {};

    // prologue: stage K-step 0 into buffer 0
    #pragma unroll
    for (int r = 0; r < 2; ++r) {
        int seg = r*4 + w;
        int row = seg*16 + srow;
        gl2lds16(Ab + (size_t)(m0+row)*C_ + skk, As[0] + seg*512);
        gl2lds16(wb + (size_t)(f0+row)*C_ + skk, Bs[0] + seg*512);
    }
    __syncthreads();

    const int NKT = C_/32;                 // 24
    for (int kt = 0; kt < NKT; ++kt) {
        const int cur = kt & 1;
        if (kt + 1 < NKT) {
            const int k0n = (kt+1)*32;
            #pragma unroll
            for (int r = 0; r < 2; ++r) {
                int seg = r*4 + w;
                int row = seg*16 + srow;
                gl2lds16(Ab + (size_t)(m0+row)*C_ + k0n + skk, As[cur^1] + seg*512);
                gl2lds16(wb + (size_t)(f0+row)*C_ + k0n + skk, Bs[cur^1] + seg*512);
            }
        }
        bfrag af[4], bf[4];
        #pragma unroll
        for (int i = 0; i < 4; ++i)
            af[i] = *(const bfrag*)(As[cur] + (wr*64 + i*16 + l15)*32 + quad*8);
        #pragma unroll
        for (int j = 0; j < 4; ++j)
            bf[j] = *(const bfrag*)(Bs[cur] + (wc*64 + j*16 + l15)*32 + quad*8);
        #pragma unroll
        for (int i = 0; i < 4; ++i)
            #pragma unroll
            for (int j = 0; j < 4; ++j)
                acc[i][j] = __builtin_amdgcn_mfma_f32_16x16x32_bf16(af[i], bf[j], acc[i][j], 0, 0, 0);
        __syncthreads();
    }

    #pragma unroll
    for (int i = 0; i < 4; ++i) {
        int mbase = m0 + wr*64 + i*16 + quad*4;
        #pragma unroll
        for (int j = 0; j < 4; ++j) {
            int f = f0 + wc*64 + j*16 + l15;
            float bv = bias[f];
            #pragma unroll
            for (int r = 0; r < 4; ++r)
                out[(size_t)(mbase + r)*C_ + f] = acc[i][j][r] + bv;
        }
    }
}

// ---------------------------------------------------------------------------
extern "C" void kernel_launch(void* const* d_in, const int* in_sizes, int n_in,
                              void* d_out, int out_size, void* d_ws, size_t ws_size,
                              hipStream_t stream) {
    const float* x      = (const float*)d_in[0];
    const float* qkv_w  = (const float*)d_in[3];
    const float* proj_w = (const float*)d_in[4];
    const float* proj_b = (const float*)d_in[5];
    float* out = (float*)d_out;

    const size_t nx = (size_t)M_ * C_;        // 3,538,944
    const size_t nq = (size_t)F3 * C_;        // 1,769,472
    const size_t np = (size_t)C_ * C_;        //   589,824
    short* xb  = (short*)d_ws;
    short* qwb = xb  + nx;
    short* pwb = qwb + nq;
    short* Qb  = pwb + np;
    short* Kb  = Qb  + nx;
    short* Vtb = Kb  + nx;
    short* Ob  = Vtb + nx;
    float* Opart = (float*)(Ob + nx);                       // SPLITS * M_*C_
    float* lpart = Opart + (size_t)SPLITS * M_ * C_;        // SPLITS * 24*N_

    const int ncast4 = (int)((nx + nq + np) / 4);
    cast_all<<<dim3((ncast4 + 255)/256), 256, 0, stream>>>(x, qkv_w, proj_w, xb);

    qkv_gemm<<<dim3(F3/128, M_/128), 256, 0, stream>>>(xb, qwb, Qb, Kb, Vtb);
    attn_mfma<<<dim3(B_*HEADS, N_/128, SPLITS), 256, 0, stream>>>(Qb, Kb, Vtb, Opart, lpart);
    attn_merge<<<dim3(((int)(nx/4) + 255)/256), 256, 0, stream>>>(Opart, lpart, Ob);
    proj_gemm<<<dim3(C_/128, M_/128), 256, 0, stream>>>(Ob, pwb, proj_b, out);
}

// Round 5
// 193.614 us; speedup vs baseline: 1.1030x; 1.0021x over previous
//
#include <hip/hip_runtime.h>

#define B_    2
#define N_    2304
#define C_    768
#define HEADS 12
#define D_    64
#define F3    2304
#define M_    (B_*N_)        // 4608
#define SPLITS 2
#define KSPAN (N_/SPLITS)    // 1152
// SCALE(0.125) * log2(e) folded into Q at qkv epilogue:
#define QSCALE 0.18033688011112042f

typedef __attribute__((ext_vector_type(8)))  short bfrag;    // 8 x bf16 (4 VGPR)
typedef __attribute__((ext_vector_type(4)))  float ffrag;    // 16x16 acc
typedef __attribute__((ext_vector_type(16))) float ffrag16;  // 32x32 acc
typedef __attribute__((ext_vector_type(4)))  unsigned ufrag; // 4 x b32 = 8 bf16
typedef __attribute__((ext_vector_type(2)))  unsigned uint2v;

__device__ __forceinline__ short f2bf(float f) {
    unsigned u = __float_as_uint(f);
    u += 0x7fff + ((u >> 16) & 1);          // RNE
    return (short)(u >> 16);
}

__device__ __forceinline__ void gl2lds16(const void* g, void* l) {
    __builtin_amdgcn_global_load_lds(
        (const __attribute__((address_space(1))) void*)g,
        (__attribute__((address_space(3))) void*)l, 16, 0, 0);
}

// Counted waits (T4): never drain the just-issued prefetch. "memory"
// clobber keeps ds_read/global ops from crossing.
__device__ __forceinline__ void wait_vm4() { asm volatile("s_waitcnt vmcnt(4)" ::: "memory"); }
__device__ __forceinline__ void wait_vm0() { asm volatile("s_waitcnt vmcnt(0)" ::: "memory"); }

// trunc-pack two fp32 -> (bf16(a) low | bf16(b) high) in ONE v_perm_b32.
// bias-safe here because numerator (PV) and denominator (l sum) both
// consume the same truncated values -> common bias cancels in the ratio.
__device__ __forceinline__ unsigned pktrunc(float a, float b) {
    return __builtin_amdgcn_perm(__float_as_uint(a), __float_as_uint(b),
                                 0x03020706u);
}

// exactly the bf16 value pktrunc keeps (bit truncation): for the l sum.
__device__ __forceinline__ float btrunc(float a) {
    return __uint_as_float(__float_as_uint(a) & 0xffff0000u);
}

// ---------------------------------------------------------------------------
// Fused fp32 -> bf16 cast of x, qkv_w, proj_w (dsts contiguous in ws).
// ---------------------------------------------------------------------------
__global__ __launch_bounds__(256) void cast_all(const float* __restrict__ x,
                                                const float* __restrict__ qw,
                                                const float* __restrict__ pw,
                                                short* __restrict__ dst) {
    const int nx4 = (M_*C_)/4, nq4 = (F3*C_)/4, np4 = (C_*C_)/4;
    int i = blockIdx.x * 256 + threadIdx.x;
    if (i >= nx4 + nq4 + np4) return;
    const float* src; int off;
    if (i < nx4)            { src = x;  off = i; }
    else if (i < nx4 + nq4) { src = qw; off = i - nx4; }
    else                    { src = pw; off = i - nx4 - nq4; }
    float4 v = ((const float4*)src)[off];
    short4 o;
    o.x = f2bf(v.x); o.y = f2bf(v.y); o.z = f2bf(v.z); o.w = f2bf(v.w);
    ((short4*)dst)[i] = o;
}

// ---------------------------------------------------------------------------
// QKV GEMM: qkv[m][f] = sum_c x[m][c]*w[f][c]  (NT), m97 structure
// + 2-phase double-buffer with COUNTED vmcnt (T4): per K-step
//   {issue 4 loads(t+1); vmcnt(4); s_barrier; ds_read+MFMA(t); s_barrier}.
//   Tile t's loads get a full compute phase + barrier of slack; the
//   just-issued prefetch is never drained (old __syncthreads did vmcnt(0)).
// + XCD-chunked blockIdx swizzle (648 % 8 == 0 -> bijective).
// Q stored pre-scaled by SCALE*log2e; V stored transposed [bh,d,n].
// ---------------------------------------------------------------------------
__global__ __launch_bounds__(256) void qkv_gemm(const short* __restrict__ xb,
                                                const short* __restrict__ wb,
                                                short* __restrict__ Qb,
                                                short* __restrict__ Kb,
                                                short* __restrict__ Vtb) {
    __shared__ short As[2][128*32];
    __shared__ short Bs[2][128*32];
    const int t = threadIdx.x;
    const int w = t >> 6, lane = t & 63;
    const int quad = lane >> 4, l15 = lane & 15;
    const int wr = w >> 1, wc = w & 1;

    const int nwg = gridDim.x * gridDim.y;
    const int bid = blockIdx.y * gridDim.x + blockIdx.x;
    const int swz = (bid & 7) * (nwg >> 3) + (bid >> 3);
    const int m0 = (swz / gridDim.x) * 128, f0 = (swz % gridDim.x) * 128;

    const int srow = lane >> 2;            // row within 16-row segment
    const int skk  = (lane & 3) * 8;       // bf16 offset within 32-col row

    ffrag acc[4][4] = {};

    // prologue: issue K-step 0 into buffer 0 (4 loads, not waited here)
    #pragma unroll
    for (int r = 0; r < 2; ++r) {
        int seg = r*4 + w;
        int row = seg*16 + srow;
        gl2lds16(xb + (size_t)(m0+row)*C_ + skk, As[0] + seg*512);
        gl2lds16(wb + (size_t)(f0+row)*C_ + skk, Bs[0] + seg*512);
    }

    const int NKT = C_/32;                 // 24
    for (int kt = 0; kt < NKT; ++kt) {
        const int cur = kt & 1;
        if (kt + 1 < NKT) {                // prefetch next K-step into buf^1
            const int k0n = (kt+1)*32;
            #pragma unroll
            for (int r = 0; r < 2; ++r) {
                int seg = r*4 + w;
                int row = seg*16 + srow;
                gl2lds16(xb + (size_t)(m0+row)*C_ + k0n + skk, As[cur^1] + seg*512);
                gl2lds16(wb + (size_t)(f0+row)*C_ + k0n + skk, Bs[cur^1] + seg*512);
            }
            wait_vm4();                    // tile kt landed; kt+1 in flight
        } else {
            wait_vm0();
        }
        __builtin_amdgcn_s_barrier();      // tile kt visible to all waves

        bfrag af[4], bf[4];
        #pragma unroll
        for (int i = 0; i < 4; ++i)
            af[i] = *(const bfrag*)(As[cur] + (wr*64 + i*16 + l15)*32 + quad*8);
        #pragma unroll
        for (int j = 0; j < 4; ++j)
            bf[j] = *(const bfrag*)(Bs[cur] + (wc*64 + j*16 + l15)*32 + quad*8);
        #pragma unroll
        for (int i = 0; i < 4; ++i)
            #pragma unroll
            for (int j = 0; j < 4; ++j)
                acc[i][j] = __builtin_amdgcn_mfma_f32_16x16x32_bf16(af[i], bf[j], acc[i][j], 0, 0, 0);
        __builtin_amdgcn_s_barrier();      // reads of buf[cur] done before overwrite
    }

    const int b   = m0 / N_;
    const int seg = f0 + wc*64;
    const int which = seg / C_;                  // 0=Q 1=K 2=V
    const int head  = (seg - which*C_) >> 6;
    const int bh    = b*HEADS + head;
    const int nbase = (m0 - b*N_) + wr*64 + quad*4;

    if (which == 0) {
        #pragma unroll
        for (int i = 0; i < 4; ++i) {
            int n0 = nbase + i*16;
            #pragma unroll
            for (int j = 0; j < 4; ++j) {
                int d = j*16 + l15;
                #pragma unroll
                for (int r = 0; r < 4; ++r)
                    Qb[((size_t)bh*N_ + n0 + r)*D_ + d] = f2bf(acc[i][j][r] * QSCALE);
            }
        }
    } else if (which == 1) {
        #pragma unroll
        for (int i = 0; i < 4; ++i) {
            int n0 = nbase + i*16;
            #pragma unroll
            for (int j = 0; j < 4; ++j) {
                int d = j*16 + l15;
                #pragma unroll
                for (int r = 0; r < 4; ++r)
                    Kb[((size_t)bh*N_ + n0 + r)*D_ + d] = f2bf(acc[i][j][r]);
            }
        }
    } else {
        #pragma unroll
        for (int i = 0; i < 4; ++i) {
            int n0 = nbase + i*16;
            #pragma unroll
            for (int j = 0; j < 4; ++j) {
                int d = j*16 + l15;
                short4 vv;
                vv.x = f2bf(acc[i][j][0]);
                vv.y = f2bf(acc[i][j][1]);
                vv.z = f2bf(acc[i][j][2]);
                vv.w = f2bf(acc[i][j][3]);
                *(short4*)(Vtb + ((size_t)bh*D_ + d)*N_ + n0) = vv;
            }
        }
    }
}

// ---------------------------------------------------------------------------
// Flash attention, 32x32x16 bf16 MFMA, no-max softmax, split-K over grid.z.
// SPLITS back to 2 (3 cost +14 MB fp32 partial writes, no occupancy gain).
// 4-wave blocks over 128 q-rows; K/V LDS double-buffered with COUNTED-vmcnt
// 2-phase pipeline (same scheme as qkv_gemm). Q tile overlays buffer set 1
// during the prologue only. P transpose via v_permlane32_swap_b32.
// l (softmax denom) = per-lane VALU sum of BIT-TRUNCATED exp values
// (exactly what PV's MFMA consumes -> bias cancels in O/l); removes the
// ones-MFMA (-20% MFMA work). Cross-half combine: one shfl_xor at epilogue.
// Grid (B*H, N/128, SPLITS). LDS rows 128B, XOR-swizzled.
// 32x32 C layout: col = lane&31, row = (reg&3) + 8*(reg>>2) + 4*(lane>>5).
// ---------------------------------------------------------------------------
__global__ __launch_bounds__(256, 4) void attn_mfma(const short* __restrict__ Qb,
                                                    const short* __restrict__ Kb,
                                                    const short* __restrict__ Vtb,
                                                    float* __restrict__ Opart,
                                                    float* __restrict__ lpart) {
    // 32 KiB total: set s at lds + s*8192 shorts (K 4096 | V 4096).
    __shared__ short lds[16384];
    const int t = threadIdx.x;
    const int w = t >> 6, lane = t & 63;
    const int l31 = lane & 31, hi = lane >> 5;
    const int bh = blockIdx.x, q0 = blockIdx.y * 128;
    const int split = blockIdx.z;
    const int kbase = split * KSPAN;
    const size_t base = (size_t)bh * N_ * D_;
    const int lrow = lane >> 3;            // row within 8-row segment
    const int lc   = (lane & 7) ^ lrow;    // swizzled source chunk

    short* Qs = lds + 8192;                // overlays set 1

    // prologue: stage Q tile (128 x 64) into set1 region, K/V tile 0 into set0
    #pragma unroll
    for (int r = 0; r < 4; ++r) {
        int s = r*4 + w;
        gl2lds16(Qb + base + (size_t)(q0 + s*8 + lrow)*D_ + lc*8, Qs + s*512);
    }
    #pragma unroll
    for (int r = 0; r < 2; ++r) {
        int s = r*4 + w;
        int row = s*8 + lrow;
        gl2lds16(Kb  + base + (size_t)(kbase+row)*D_ + lc*8,    lds + s*512);
        gl2lds16(Vtb + (size_t)(bh*D_ + row)*N_ + kbase + lc*8, lds + 4096 + s*512);
    }
    __syncthreads();                       // Q + tile0 staged (full drain, once)

    // hoist Q B-frags (loop-invariant)
    bfrag qf[4];
    {
        int row = w*32 + l31, r7 = row & 7;
        #pragma unroll
        for (int kc = 0; kc < 4; ++kc)
            qf[kc] = *(const bfrag*)(Qs + row*64 + ((kc*2 + hi) ^ r7)*8);
    }
    __syncthreads();                       // Q-frag reads done before set1 reuse

    ffrag16 oacc[2];
    #pragma unroll
    for (int r = 0; r < 16; ++r) { oacc[0][r] = 0.f; oacc[1][r] = 0.f; }
    float llane = 0.f;                     // softmax denom partial (this half)

    const int NT = KSPAN / 64;             // 18
    for (int ti = 0; ti < NT; ++ti) {
        const int cur = ti & 1;
        const short* Kc = lds + cur*8192;
        const short* Vc = Kc + 4096;

        // issue next tile's staging; counted wait — tile ti's loads have had
        // a full iteration to complete, prefetch stays in flight
        if (ti + 1 < NT) {
            short* Kn = lds + (cur^1)*8192;
            const int k0n = kbase + (ti+1)*64;
            #pragma unroll
            for (int r = 0; r < 2; ++r) {
                int s = r*4 + w;
                int row = s*8 + lrow;
                gl2lds16(Kb  + base + (size_t)(k0n+row)*D_ + lc*8,    Kn + s*512);
                gl2lds16(Vtb + (size_t)(bh*D_ + row)*N_ + k0n + lc*8, Kn + 4096 + s*512);
            }
            wait_vm4();
        } else {
            wait_vm0();
        }
        __builtin_amdgcn_s_barrier();      // tile ti visible to all waves

        ufrag pfr[4];                      // A-frags for PV, kc = kt*2 + {lo,hi}
        #pragma unroll
        for (int kt = 0; kt < 2; ++kt) {
            // S^T tile: rows k (reg-dist), cols q (lane)
            ffrag16 s;
            #pragma unroll
            for (int r = 0; r < 16; ++r) s[r] = 0.f;
            int row = kt*32 + l31, r7 = row & 7;
            __builtin_amdgcn_s_setprio(1);
            #pragma unroll
            for (int kc = 0; kc < 4; ++kc) {
                bfrag kf = *(const bfrag*)(Kc + row*64 + ((kc*2 + hi) ^ r7)*8);
                s = __builtin_amdgcn_mfma_f32_32x32x16_bf16(kf, qf[kc], s, 0, 0, 0);
            }
            __builtin_amdgcn_s_setprio(0);
            // p = 2^s; trunc-pack to bf16 pairs (k even-adjacent)
            #pragma unroll
            for (int r = 0; r < 16; ++r)
                s[r] = __builtin_amdgcn_exp2f(s[r]);
            // l partial: sum of truncated values this lane holds (16 k's of
            // this lane's q column) — replaces the ones-MFMA.
            {
                float t0 = 0.f, t1 = 0.f;
                #pragma unroll
                for (int r = 0; r < 16; r += 2) {
                    t0 += btrunc(s[r]);
                    t1 += btrunc(s[r+1]);
                }
                llane += t0 + t1;
            }
            // group g (regs 4g..4g+3) holds k_local = 8g + 4hi + {0..3}
            unsigned q01_0 = pktrunc(s[0],  s[1]),  q23_0 = pktrunc(s[2],  s[3]);
            unsigned q01_1 = pktrunc(s[4],  s[5]),  q23_1 = pktrunc(s[6],  s[7]);
            unsigned q01_2 = pktrunc(s[8],  s[9]),  q23_2 = pktrunc(s[10], s[11]);
            unsigned q01_3 = pktrunc(s[12], s[13]), q23_3 = pktrunc(s[14], s[15]);
            // v_permlane32_swap: {a',b'} with a' = [a.lo32 | b.lo32],
            // b' = [a.hi32 | b.hi32] — exactly the lo/hi fragment exchange.
            uint2v e0 = __builtin_amdgcn_permlane32_swap(q01_0, q01_1, false, false);
            uint2v e1 = __builtin_amdgcn_permlane32_swap(q23_0, q23_1, false, false);
            uint2v e2 = __builtin_amdgcn_permlane32_swap(q01_2, q01_3, false, false);
            uint2v e3 = __builtin_amdgcn_permlane32_swap(q23_2, q23_3, false, false);
            ufrag lo, hif;
            lo[0]  = e0[0]; lo[1]  = e1[0]; lo[2]  = e0[1]; lo[3]  = e1[1];
            hif[0] = e2[0]; hif[1] = e3[0]; hif[2] = e2[1]; hif[3] = e3[1];
            pfr[kt*2]     = lo;            // k_local 0-15  (P[q][8hi+j] form)
            pfr[kt*2 + 1] = hif;           // k_local 16-31
        }

        // O += P V  (consumes the same truncated P frags as the l sum)
        __builtin_amdgcn_s_setprio(1);
        #pragma unroll
        for (int kc = 0; kc < 4; ++kc) {
            bfrag pf = __builtin_bit_cast(bfrag, pfr[kc]);
            #pragma unroll
            for (int dt = 0; dt < 2; ++dt) {
                int row = dt*32 + l31, r7 = row & 7;
                bfrag vf = *(const bfrag*)(Vc + row*64 + ((kc*2 + hi) ^ r7)*8);
                oacc[dt] = __builtin_amdgcn_mfma_f32_32x32x16_bf16(pf, vf, oacc[dt], 0, 0, 0);
            }
        }
        __builtin_amdgcn_s_setprio(0);
        __builtin_amdgcn_s_barrier();      // reads of buf[cur] done before overwrite
    }

    const int b = bh / HEADS, head = bh - b*HEADS;
    float* Op = Opart + (size_t)split * M_ * C_;
    float* lp = lpart + (size_t)split * (B_*HEADS) * N_;

    // combine the two 16-k halves of l (partner lane has same q, other hi)
    {
        float lpart_other = __shfl_xor(llane, 32, 64);
        float ltot = llane + lpart_other;
        if (hi == 0)
            lp[bh*N_ + q0 + w*32 + l31] = ltot;
    }

    #pragma unroll
    for (int dt = 0; dt < 2; ++dt)
        #pragma unroll
        for (int r = 0; r < 16; ++r) {
            int n = q0 + w*32 + (r & 3) + 8*(r >> 2) + 4*hi;
            int c = head*D_ + dt*32 + l31;
            Op[((size_t)b*N_ + n)*C_ + c] = oacc[dt][r];
        }
}

// ---------------------------------------------------------------------------
// Merge split-K partials: Ob = (sum_s O_s) / (sum_s l_s), bf16 out.
// ---------------------------------------------------------------------------
__global__ __launch_bounds__(256) void attn_merge(const float* __restrict__ Opart,
                                                  const float* __restrict__ lpart,
                                                  short* __restrict__ Ob) {
    int i = blockIdx.x * 256 + threadIdx.x;          // over M_*C_/4
    int m = i / (C_/4);
    int c = (i - m*(C_/4)) * 4;
    int b = m / N_, n = m - b*N_;
    int bh = b*HEADS + (c >> 6);
    float4 o0 = ((const float4*)Opart)[i];
    float4 o1 = ((const float4*)(Opart + (size_t)M_*C_))[i];
    float l = lpart[bh*N_ + n] + lpart[(B_*HEADS)*N_ + bh*N_ + n];
    float inv = 1.f / l;
    short4 o;
    o.x = f2bf((o0.x + o1.x) * inv);
    o.y = f2bf((o0.y + o1.y) * inv);
    o.z = f2bf((o0.z + o1.z) * inv);
    o.w = f2bf((o0.w + o1.w) * inv);
    ((short4*)Ob)[i] = o;
}

// ---------------------------------------------------------------------------
// Proj GEMM: out[m][f] = sum_c O[m][c]*w[f][c] + bias[f], fp32 out.
// Same counted-vmcnt pipeline + XCD swizzle (216 blocks % 8 == 0).
// ---------------------------------------------------------------------------
__global__ __launch_bounds__(256) void proj_gemm(const short* __restrict__ Ab,
                                                 const short* __restrict__ wb,
                                                 const float* __restrict__ bias,
                                                 float* __restrict__ out) {
    __shared__ short As[2][128*32];
    __shared__ short Bs[2][128*32];
    const int t = threadIdx.x;
    const int w = t >> 6, lane = t & 63;
    const int quad = lane >> 4, l15 = lane & 15;
    const int wr = w >> 1, wc = w & 1;

    const int nwg = gridDim.x * gridDim.y;
    const int bid = blockIdx.y * gridDim.x + blockIdx.x;
    const int swz = (bid & 7) * (nwg >> 3) + (bid >> 3);
    const int m0 = (swz / gridDim.x) * 128, f0 = (swz % gridDim.x) * 128;

    const int srow = lane >> 2;
    const int skk  = (lane & 3) * 8;

    ffrag acc[4][4] = {};

    // prologue: issue K-step 0 into buffer 0
    #pragma unroll
    for (int r = 0; r < 2; ++r) {
        int seg = r*4 + w;
        int row = seg*16 + srow;
        gl2lds16(Ab + (size_t)(m0+row)*C_ + skk, As[0] + seg*512);
        gl2lds16(wb + (size_t)(f0+row)*C_ + skk, Bs[0] + seg*512);
    }

    const int NKT = C_/32;                 // 24
    for (int kt = 0; kt < NKT; ++kt) {
        const int cur = kt & 1;
        if (kt + 1 < NKT) {
            const int k0n = (kt+1)*32;
            #pragma unroll
            for (int r = 0; r < 2; ++r) {
                int seg = r*4 + w;
                int row = seg*16 + srow;
                gl2lds16(Ab + (size_t)(m0+row)*C_ + k0n + skk, As[cur^1] + seg*512);
                gl2lds16(wb + (size_t)(f0+row)*C_ + k0n + skk, Bs[cur^1] + seg*512);
            }
            wait_vm4();
        } else {
            wait_vm0();
        }
        __builtin_amdgcn_s_barrier();

        bfrag af[4], bf[4];
        #pragma unroll
        for (int i = 0; i < 4; ++i)
            af[i] = *(const bfrag*)(As[cur] + (wr*64 + i*16 + l15)*32 + quad*8);
        #pragma unroll
        for (int j = 0; j < 4; ++j)
            bf[j] = *(const bfrag*)(Bs[cur] + (wc*64 + j*16 + l15)*32 + quad*8);
        #pragma unroll
        for (int i = 0; i < 4; ++i)
            #pragma unroll
            for (int j = 0; j < 4; ++j)
                acc[i][j] = __builtin_amdgcn_mfma_f32_16x16x32_bf16(af[i], bf[j], acc[i][j], 0, 0, 0);
        __builtin_amdgcn_s_barrier();
    }

    #pragma unroll
    for (int i = 0; i < 4; ++i) {
        int mbase = m0 + wr*64 + i*16 + quad*4;
        #pragma unroll
        for (int j = 0; j < 4; ++j) {
            int f = f0 + wc*64 + j*16 + l15;
            float bv = bias[f];
            #pragma unroll
            for (int r = 0; r < 4; ++r)
                out[(size_t)(mbase + r)*C_ + f] = acc[i][j][r] + bv;
        }
    }
}

// ---------------------------------------------------------------------------
extern "C" void kernel_launch(void* const* d_in, const int* in_sizes, int n_in,
                              void* d_out, int out_size, void* d_ws, size_t ws_size,
                              hipStream_t stream) {
    const float* x      = (const float*)d_in[0];
    const float* qkv_w  = (const float*)d_in[3];
    const float* proj_w = (const float*)d_in[4];
    const float* proj_b = (const float*)d_in[5];
    float* out = (float*)d_out;

    const size_t nx = (size_t)M_ * C_;        // 3,538,944
    const size_t nq = (size_t)F3 * C_;        // 1,769,472
    const size_t np = (size_t)C_ * C_;        //   589,824
    short* xb  = (short*)d_ws;
    short* qwb = xb  + nx;
    short* pwb = qwb + nq;
    short* Qb  = pwb + np;
    short* Kb  = Qb  + nx;
    short* Vtb = Kb  + nx;
    short* Ob  = Vtb + nx;
    float* Opart = (float*)(Ob + nx);                       // SPLITS * M_*C_
    float* lpart = Opart + (size_t)SPLITS * M_ * C_;        // SPLITS * 24*N_

    const int ncast4 = (int)((nx + nq + np) / 4);
    cast_all<<<dim3((ncast4 + 255)/256), 256, 0, stream>>>(x, qkv_w, proj_w, xb);

    qkv_gemm<<<dim3(F3/128, M_/128), 256, 0, stream>>>(xb, qwb, Qb, Kb, Vtb);
    attn_mfma<<<dim3(B_*HEADS, N_/128, SPLITS), 256, 0, stream>>>(Qb, Kb, Vtb, Opart, lpart);
    attn_merge<<<dim3(((int)(nx/4) + 255)/256), 256, 0, stream>>>(Opart, lpart, Ob);
    proj_gemm<<<dim3(C_/128, M_/128), 256, 0, stream>>>(Ob, pwb, proj_b, out);
}